// Round 10
// baseline (217.816 us; speedup 1.0000x reference)
//
#include <hip/hip_runtime.h>
#include <hip/hip_bf16.h>

#define BB 512
#define TT 2048
#define SS 128
#define LL 64
#define PP (TT - LL + 1)   // 1985

#define XF_N  2128                // staged fp32 x (zero-padded past 2048)
#define XCP_W 530                 // 8B words per shifted copy; (2*530)%32==4 ->
                                  // copies start 4 banks apart => reads tile 32 banks

typedef __attribute__((ext_vector_type(8))) short    short8;
typedef __attribute__((ext_vector_type(4))) float    float4v;
typedef __attribute__((ext_vector_type(16))) float   f32x16;
typedef __attribute__((ext_vector_type(4))) unsigned uint4v;

__device__ __forceinline__ unsigned f2bf1(float f) {
  union { float f; unsigned u; } v; v.f = f;
  return (v.u + 0x7FFFu + ((v.u >> 16) & 1u)) >> 16;   // RNE fp32->bf16
}

// ---- single fused kernel: 1 block (512 thr, 8 waves) per sample ----
// Round-10: r9's 32x32x16 port was numerically correct but violated rule
// #20 — rmax[(H)*2+ct] with runtime H (unroll-1 h-loop) put the accumulator
// array in SCRATCH: 165MB FETCH + 169MB WRITE per dispatch, MfmaUtil 8%,
// 79us. Fix: per-h static scalars rm[ct] (ct fully unrolled) and the
// shfl-32 merge + wred store moved into the h-loop tail (h only feeds an
// LDS ADDRESS, never a register-array index). Everything else identical.
// Per wave: 256 windows (8 row-tiles of 32) x 128 shapelets (2 halves x 2
// col-tiles of 32). B from frag-major shbF[kb*2+hi][s]; A from xcp ring
// (2 new ds_read_b128/mt); C-init = -c0/2 via HW-verified 32x32 C/D layout
// col=lane&31, row=(reg&3)+8*(reg>>2)+4*(lane>>5)  [verified by r9 pass].
// d2 = c0[p] + s2c[s] - 2*cross; g = max_p(cross - c0/2);
// out = sqrt(s2c - 2g). Masked windows (p>=1985) carry c0h = -INF.
__global__ __launch_bounds__(512, 4)
void shapelet_fused(const float* __restrict__ x, const float* __restrict__ shg,
                    float* __restrict__ out) {
  __shared__ __align__(16) float xf[XF_N];
  __shared__ __align__(16) unsigned long long xcp[8][XCP_W];
  __shared__ float c0h[2048];
  __shared__ __align__(16) uint4v shbF[8][129];   // [kb*2+hi][s]; 129 spreads write banks
  __shared__ float s2cl[SS];
  __shared__ float wred[8 * SS];

  const int t = threadIdx.x;
  const int b = blockIdx.x;
  const int lane = t & 63, wave = t >> 6;
  const int l31 = lane & 31, hi = lane >> 5;

  // ---- stage x[b] (8 KB) into LDS, zero-pad to XF_N ----
  for (int idx = t; idx < XF_N / 4; idx += 512) {
    const int g0 = 4 * idx;
    float4v v = {0.f, 0.f, 0.f, 0.f};
    if (g0 + 3 < TT) v = *(const float4v*)(x + (size_t)b * TT + g0);
    *(float4v*)(xf + 4 * idx) = v;
  }

  // ---- shapelet prep: center, bf16-pack, frag-major store ----
  // thread t: row s = t>>2, k-quarter part = t&3 (16 floats = kb 'part')
  {
    const int s = t >> 2, part = t & 3;
    const float4v* sp = (const float4v*)(shg + s * LL + part * 16);
    float4v r0 = sp[0], r1 = sp[1], r2 = sp[2], r3 = sp[3];
    float sum = 0.f, sq = 0.f;
    #pragma unroll
    for (int k = 0; k < 4; ++k) {
      const float4v rv = (k == 0) ? r0 : (k == 1) ? r1 : (k == 2) ? r2 : r3;
      sum += (rv[0] + rv[1]) + (rv[2] + rv[3]);
      sq = fmaf(rv[0], rv[0], sq); sq = fmaf(rv[1], rv[1], sq);
      sq = fmaf(rv[2], rv[2], sq); sq = fmaf(rv[3], rv[3], sq);
    }
    sum += __shfl_xor(sum, 1); sum += __shfl_xor(sum, 2);
    sq  += __shfl_xor(sq, 1);  sq  += __shfl_xor(sq, 2);
    const float mean = sum * (1.f / 64.f);

    unsigned pk[8];
    #pragma unroll
    for (int k = 0; k < 4; ++k) {
      const float4v rv = (k == 0) ? r0 : (k == 1) ? r1 : (k == 2) ? r2 : r3;
      pk[2 * k]     = f2bf1(rv[0] - mean) | (f2bf1(rv[1] - mean) << 16);
      pk[2 * k + 1] = f2bf1(rv[2] - mean) | (f2bf1(rv[3] - mean) << 16);
    }
    // k-range of pk[0..3] = part*16 + [0,8) -> plane (part,hi=0);
    // pk[4..7] = part*16 + [8,16) -> plane (part,hi=1)
    uint4v w0v = {pk[0], pk[1], pk[2], pk[3]};
    uint4v w1v = {pk[4], pk[5], pk[6], pk[7]};
    shbF[part * 2 + 0][s] = w0v;
    shbF[part * 2 + 1][s] = w1v;
    if (part == 0) s2cl[s] = sq;      // s2c = raw sum of squares
  }

  __syncthreads();

  // ---- build 8 element-shifted bf16 copies of xf ----
  for (int w = t; w < XCP_W; w += 512) {
    const float4v* xf4 = (const float4v*)xf;
    float4v A = xf4[w], Bv = xf4[w + 1], Cv = xf4[w + 2];
    unsigned bfx[11];
    #pragma unroll
    for (int k = 0; k < 4; ++k) bfx[k] = f2bf1(A[k]);
    #pragma unroll
    for (int k = 0; k < 4; ++k) bfx[4 + k] = f2bf1(Bv[k]);
    #pragma unroll
    for (int k = 0; k < 3; ++k) bfx[8 + k] = f2bf1(Cv[k]);
    #pragma unroll
    for (int c = 0; c < 8; ++c) {
      unsigned long long pkw =
          (unsigned long long)bfx[c] |
          ((unsigned long long)bfx[c + 1] << 16) |
          ((unsigned long long)bfx[c + 2] << 32) |
          ((unsigned long long)bfx[c + 3] << 48);
      xcp[c][w] = pkw;
    }
  }

  // ---- window stats: thread t -> windows 4t..4t+3 (rolling, capped unroll) ----
  {
    const float4v* xf4 = (const float4v*)xf;
    float S = 0.f, Q = 0.f;
    float4v v0 = xf4[t];
    float4v vcur = v0;
    #pragma unroll 4
    for (int ch = 0; ch < 16; ++ch) {
      S += (vcur[0] + vcur[1]) + (vcur[2] + vcur[3]);
      Q = fmaf(vcur[0], vcur[0], Q); Q = fmaf(vcur[1], vcur[1], Q);
      Q = fmaf(vcur[2], vcur[2], Q); Q = fmaf(vcur[3], vcur[3], Q);
      vcur = xf4[t + ch + 1];           // after loop: vcur = xf4[t+16]
    }
    const float4v vN = vcur;
    const int p0s = 4 * t;
    #pragma unroll
    for (int r = 0; r < 4; ++r) {
      const bool valid = (p0s + r) < PP;
      const float c0 = Q - S * S * (1.f / 64.f);
      c0h[p0s + r] = valid ? (-0.5f * c0) : -INFINITY;
      if (r < 3) {
        const float vin = vN[r], vout = v0[r];
        S += vin - vout;
        Q += fmaf(vin, vin, -vout * vout);
      }
    }
  }

  __syncthreads();

  // ---- main MFMA loop: 32x32x16, 2 halves x 8 row-tiles x 2 col-tiles ----
  // A element for (mt,kb): e = wave*256 + 32mt + l31 + 8hi + 16kb
  //   -> copy = l31&7, word = wave*64 + 2*(l31>>3) + 2*hi + 8mt + 4kb.
  //      Ring: frag(mt,2)=frag(mt+1,0), frag(mt,3)=frag(mt+1,1).
  //      Max word idx: wave7 -> 456 + 68 + 1 = 525 < 530 (in bounds).
  // C-init: cin[4g+j] = c0h[wave*256 + 32mt + 8g + 4hi + j]  (broadcast reads)
  const unsigned long long* xc = &xcp[l31 & 7][0];
  const int W0 = wave * 64 + 2 * (l31 >> 3) + 2 * hi;
  const int base = wave * 256;

#define MT_BODY(MT, A0, A1, A2, A3)                                           \
  {                                                                           \
    f32x16 cin;                                                               \
    _Pragma("unroll")                                                         \
    for (int g = 0; g < 4; ++g) {                                             \
      const float4v cg = *(const float4v*)&c0h[base + 32 * (MT) + 8 * g + 4 * hi]; \
      cin[4 * g + 0] = cg[0]; cin[4 * g + 1] = cg[1];                         \
      cin[4 * g + 2] = cg[2]; cin[4 * g + 3] = cg[3];                         \
    }                                                                         \
    _Pragma("unroll")                                                         \
    for (int ct = 0; ct < 2; ++ct) {                                          \
      f32x16 acc = __builtin_amdgcn_mfma_f32_32x32x16_bf16(A0, bB[ct][0], cin, 0, 0, 0); \
      acc = __builtin_amdgcn_mfma_f32_32x32x16_bf16(A1, bB[ct][1], acc, 0, 0, 0); \
      acc = __builtin_amdgcn_mfma_f32_32x32x16_bf16(A2, bB[ct][2], acc, 0, 0, 0); \
      acc = __builtin_amdgcn_mfma_f32_32x32x16_bf16(A3, bB[ct][3], acc, 0, 0, 0); \
      const float t0 = fmaxf(fmaxf(acc[0], acc[1]), acc[2]);                  \
      const float t1 = fmaxf(fmaxf(acc[3], acc[4]), acc[5]);                  \
      const float t2 = fmaxf(fmaxf(acc[6], acc[7]), acc[8]);                  \
      const float t3 = fmaxf(fmaxf(acc[9], acc[10]), acc[11]);                \
      const float t4 = fmaxf(fmaxf(acc[12], acc[13]), acc[14]);               \
      const float u0 = fmaxf(fmaxf(t0, t1), t2);                              \
      const float u1 = fmaxf(fmaxf(t3, t4), acc[15]);                         \
      rm[ct] = fmaxf(fmaxf(u0, u1), rm[ct]);                                  \
    }                                                                         \
  }

  #pragma unroll 1
  for (int h = 0; h < 2; ++h) {
    // B fragments: contiguous conflict-free reads from frag-major store
    short8 bB[2][4];
    #pragma unroll
    for (int ct = 0; ct < 2; ++ct)
      #pragma unroll
      for (int kb = 0; kb < 4; ++kb)
        bB[ct][kb] = *(const short8*)&shbF[kb * 2 + hi][h * 64 + ct * 32 + l31];

    // per-h accumulators: indexed ONLY by fully-unrolled ct -> registers
    float rm[2] = {-INFINITY, -INFINITY};

    short8 a0 = *(const short8*)&xc[W0];
    short8 a1 = *(const short8*)&xc[W0 + 4];
    short8 a2 = *(const short8*)&xc[W0 + 8];
    short8 a3 = *(const short8*)&xc[W0 + 12];

    MT_BODY(0, a0, a1, a2, a3)

    #pragma unroll 2
    for (int mt = 1; mt < 8; ++mt) {
      a0 = a2; a1 = a3;
      a2 = *(const short8*)&xc[W0 + 8 * mt + 8];
      a3 = *(const short8*)&xc[W0 + 8 * mt + 12];
      MT_BODY(mt, a0, a1, a2, a3)
    }

    // merge hi-halves (lanes l / l+32 share shapelet s = (h*2+ct)*32 + l31),
    // store per-wave result; h feeds only an LDS ADDRESS (runtime-safe).
    #pragma unroll
    for (int ct = 0; ct < 2; ++ct) {
      float v = rm[ct];
      v = fmaxf(v, __shfl_xor(v, 32));
      if (hi == 0) wred[wave * SS + (h * 2 + ct) * 32 + l31] = v;
    }
  }
#undef MT_BODY

  __syncthreads();

  if (t < SS) {
    float v = wred[t];
    #pragma unroll
    for (int w = 1; w < 8; ++w) v = fmaxf(v, wred[w * SS + t]);
    const float d2 = fmaf(-2.f, v, s2cl[t]);
    out[(size_t)b * SS + t] = sqrtf(fmaxf(d2, 0.f));
  }
}

extern "C" void kernel_launch(void* const* d_in, const int* in_sizes, int n_in,
                              void* d_out, int out_size, void* d_ws, size_t ws_size,
                              hipStream_t stream) {
  const float* x  = (const float*)d_in[0];
  const float* sh = (const float*)d_in[1];
  float* out = (float*)d_out;
  shapelet_fused<<<dim3(BB), dim3(512), 0, stream>>>(x, sh, out);
}

// Round 11
// 69.346 us; speedup vs baseline: 3.1410x; 3.1410x over previous
//
#include <hip/hip_runtime.h>
#include <hip/hip_bf16.h>

#define BB 512
#define TT 2048
#define SS 128
#define LL 64
#define PP (TT - LL + 1)   // 1985

#define XF_N  2128                // staged fp32 x (zero-padded past 2048)
#define XCP_W 530                 // 8B words per shifted copy; (2*530)%32==4 ->
                                  // copies start 4 banks apart => reads tile 32 banks
#define SH_ROW_SHORTS 72          // 64 data + 8 pad shorts (row stride 144 B)

typedef __attribute__((ext_vector_type(8))) short    short8;
typedef __attribute__((ext_vector_type(4))) float    float4v;
typedef __attribute__((ext_vector_type(4))) unsigned uint4v;

__device__ __forceinline__ unsigned f2bf1(float f) {
  union { float f; unsigned u; } v; v.f = f;
  return (v.u + 0x7FFFu + ((v.u >> 16) & 1u)) >> 16;   // RNE fp32->bf16
}

// ---- single fused kernel: 1 block (512 thr, 8 waves) per sample ----
// ROUND-11: revert to the round-8 best (69.48us). r9/r10 lesson: the
// 32x32x16 f32x16-accumulator structure spills structurally at the
// 128-VGPR/2-blocks-per-CU cap (unified-file split: 64 arch VGPR + AGPR
// half; bB+ring+cin+acc don't fit) -> 165-354MB scratch traffic, 3x
// regression. 16x16x32 with float4 accs is the right shape at this
// occupancy.
// Partition: wave w owns windows [w*256, w*256+256) x ALL 128 shapelets
// (bf[2][8] = 64 VGPRs); 1 A-read + 1 c0-read feed 16 MFMAs per iter.
// d2 = c0[p] + s2c[s] - 2*cross(x, centered_s); C-init = -c0/2;
// g = max_p(cross - c0/2); out = sqrt(s2c - 2g), s2c = raw sum(s^2).
// fmax tree in max3-fusable nested-triple form (associative -> bit-exact).
__global__ __launch_bounds__(512, 4)
void shapelet_fused(const float* __restrict__ x, const float* __restrict__ shg,
                    float* __restrict__ out) {
  __shared__ __align__(16) float xf[XF_N];
  __shared__ __align__(16) unsigned long long xcp[8][XCP_W];
  __shared__ float c0h[2048];
  __shared__ __align__(16) short shb[SS * SH_ROW_SHORTS];
  __shared__ float s2cl[SS];
  __shared__ float wred[8 * SS];

  const int t = threadIdx.x;
  const int b = blockIdx.x;
  const int lane = t & 63, wave = t >> 6;
  const int n = lane & 15, q = lane >> 4;
  const int pq = wave;                 // 8 window-groups of 256

  // ---- stage x[b] (8 KB) into LDS, zero-pad to XF_N ----
  for (int idx = t; idx < XF_N / 4; idx += 512) {
    const int g0 = 4 * idx;
    float4v v = {0.f, 0.f, 0.f, 0.f};
    if (g0 + 3 < TT) v = *(const float4v*)(x + (size_t)b * TT + g0);
    *(float4v*)(xf + 4 * idx) = v;
  }

  // ---- shapelet prep (redundant per block; 32 KB, L2-resident) ----
  // thread t: row s = t>>2, quarter part = t&3 (16 floats)
  {
    const int s = t >> 2, part = t & 3;
    const float4v* sp = (const float4v*)(shg + s * LL + part * 16);
    float4v r0 = sp[0], r1 = sp[1], r2 = sp[2], r3 = sp[3];
    float sum = 0.f, sq = 0.f;
    #pragma unroll
    for (int k = 0; k < 4; ++k) {
      const float4v rv = (k == 0) ? r0 : (k == 1) ? r1 : (k == 2) ? r2 : r3;
      sum += (rv[0] + rv[1]) + (rv[2] + rv[3]);
      sq = fmaf(rv[0], rv[0], sq); sq = fmaf(rv[1], rv[1], sq);
      sq = fmaf(rv[2], rv[2], sq); sq = fmaf(rv[3], rv[3], sq);
    }
    sum += __shfl_xor(sum, 1); sum += __shfl_xor(sum, 2);
    sq  += __shfl_xor(sq, 1);  sq  += __shfl_xor(sq, 2);
    const float mean = sum * (1.f / 64.f);

    unsigned pk[8];
    #pragma unroll
    for (int k = 0; k < 4; ++k) {
      const float4v rv = (k == 0) ? r0 : (k == 1) ? r1 : (k == 2) ? r2 : r3;
      pk[2 * k]     = f2bf1(rv[0] - mean) | (f2bf1(rv[1] - mean) << 16);
      pk[2 * k + 1] = f2bf1(rv[2] - mean) | (f2bf1(rv[3] - mean) << 16);
    }
    unsigned* shbw = (unsigned*)shb;
    const int dw = s * (SH_ROW_SHORTS / 2) + part * 8;   // 16B aligned
    uint4v w0v = {pk[0], pk[1], pk[2], pk[3]};
    uint4v w1v = {pk[4], pk[5], pk[6], pk[7]};
    *(uint4v*)(shbw + dw) = w0v;
    *(uint4v*)(shbw + dw + 4) = w1v;
    if (part == 0) s2cl[s] = sq;      // s2c = raw sum of squares
  }

  __syncthreads();

  // ---- B fragments from LDS shapelets: ALL 128 rows per wave ----
  short8 bf[2][8];
  #pragma unroll
  for (int st = 0; st < 8; ++st) {
    const int row = st * 16 + n;
    bf[0][st] = *(const short8*)(shb + row * SH_ROW_SHORTS + q * 8);
    bf[1][st] = *(const short8*)(shb + row * SH_ROW_SHORTS + 32 + q * 8);
  }

  // ---- build 8 element-shifted bf16 copies of xf ----
  for (int w = t; w < XCP_W; w += 512) {
    const float4v* xf4 = (const float4v*)xf;
    float4v A = xf4[w], Bv = xf4[w + 1], Cv = xf4[w + 2];
    unsigned bfx[11];
    #pragma unroll
    for (int k = 0; k < 4; ++k) bfx[k] = f2bf1(A[k]);
    #pragma unroll
    for (int k = 0; k < 4; ++k) bfx[4 + k] = f2bf1(Bv[k]);
    #pragma unroll
    for (int k = 0; k < 3; ++k) bfx[8 + k] = f2bf1(Cv[k]);
    #pragma unroll
    for (int c = 0; c < 8; ++c) {
      unsigned long long pkw =
          (unsigned long long)bfx[c] |
          ((unsigned long long)bfx[c + 1] << 16) |
          ((unsigned long long)bfx[c + 2] << 32) |
          ((unsigned long long)bfx[c + 3] << 48);
      xcp[c][w] = pkw;
    }
  }

  // ---- window stats: thread t -> windows 4t..4t+3 (rolling, capped unroll) ----
  {
    const float4v* xf4 = (const float4v*)xf;
    float S = 0.f, Q = 0.f;
    float4v v0 = xf4[t];
    float4v vcur = v0;
    #pragma unroll 4
    for (int ch = 0; ch < 16; ++ch) {
      S += (vcur[0] + vcur[1]) + (vcur[2] + vcur[3]);
      Q = fmaf(vcur[0], vcur[0], Q); Q = fmaf(vcur[1], vcur[1], Q);
      Q = fmaf(vcur[2], vcur[2], Q); Q = fmaf(vcur[3], vcur[3], Q);
      vcur = xf4[t + ch + 1];           // after loop: vcur = xf4[t+16]
    }
    const float4v vN = vcur;
    const int p0s = 4 * t;
    #pragma unroll
    for (int r = 0; r < 4; ++r) {
      const bool valid = (p0s + r) < PP;
      const float c0 = Q - S * S * (1.f / 64.f);
      c0h[p0s + r] = valid ? (-0.5f * c0) : -INFINITY;
      if (r < 3) {
        const float vin = vN[r], vout = v0[r];
        S += vin - vout;
        Q += fmaf(vin, vin, -vout * vout);
      }
    }
  }

  __syncthreads();

  // ---- main MFMA loop: 16 iters x (1 A-read + 1 c0-read + 16 MFMA) ----
  // words: frag(mt,kb0) = w0+4mt ; frag(mt,kb1) = w0+4mt+8 = frag(mt+2,kb0).
  const int cc = n & 7;
  const int lw = 2 * q + 2 * (n >> 3);          // even => aligned ds_read_b128
  const unsigned long long* xc = &xcp[cc][0];
  const int base = pq * 256;
  const int w0 = (base >> 2) + lw;

  float rmax[8];
  #pragma unroll
  for (int st = 0; st < 8; ++st) rmax[st] = -INFINITY;

  short8 h0 = *(const short8*)&xc[w0];          // frag(base,    kb0)
  short8 h1 = *(const short8*)&xc[w0 + 4];      // frag(base+16, kb0)

  #pragma unroll 2
  for (int mt = 0; mt < 16; ++mt) {
    const short8 l = *(const short8*)&xc[w0 + 4 * mt + 8];   // frag(p0, kb1)
    const float4v c0v = *(const float4v*)&c0h[base + 16 * mt + 4 * q];

    #pragma unroll
    for (int st = 0; st < 8; ++st) {
      float4v acc = __builtin_amdgcn_mfma_f32_16x16x32_bf16(h0, bf[0][st], c0v, 0, 0, 0);
      acc = __builtin_amdgcn_mfma_f32_16x16x32_bf16(l, bf[1][st], acc, 0, 0, 0);
      // nested pairs -> clang fuses v_max3_f32; max is associative (exact)
      const float t1 = fmaxf(fmaxf(acc[0], acc[1]), acc[2]);
      rmax[st] = fmaxf(fmaxf(t1, acc[3]), rmax[st]);
    }
    h0 = h1;          // frag(p0, kb1) == frag(p0+32, kb0)
    h1 = l;
  }

  // ---- reduce: across q (shfl), then across 8 waves (LDS), write out ----
  #pragma unroll
  for (int st = 0; st < 8; ++st) {
    float v = rmax[st];
    v = fmaxf(v, __shfl_xor(v, 16));
    v = fmaxf(v, __shfl_xor(v, 32));
    if (q == 0) wred[wave * SS + st * 16 + n] = v;
  }
  __syncthreads();

  if (t < SS) {
    float v = wred[t];
    #pragma unroll
    for (int w = 1; w < 8; ++w) v = fmaxf(v, wred[w * SS + t]);
    const float d2 = fmaf(-2.f, v, s2cl[t]);
    out[(size_t)b * SS + t] = sqrtf(fmaxf(d2, 0.f));
  }
}

extern "C" void kernel_launch(void* const* d_in, const int* in_sizes, int n_in,
                              void* d_out, int out_size, void* d_ws, size_t ws_size,
                              hipStream_t stream) {
  const float* x  = (const float*)d_in[0];
  const float* sh = (const float*)d_in[1];
  float* out = (float*)d_out;
  shapelet_fused<<<dim3(BB), dim3(512), 0, stream>>>(x, sh, out);
}

// Round 12
// 69.171 us; speedup vs baseline: 3.1490x; 1.0025x over previous
//
#include <hip/hip_runtime.h>
#include <hip/hip_bf16.h>

#define BB 512
#define TT 2048
#define SS 128
#define LL 64
#define PP (TT - LL + 1)   // 1985

#define XF_N  2128                // staged fp32 x (zero-padded past 2048)
#define XCP_W 530                 // 8B words per shifted copy; (2*530)%32==4 ->
                                  // copies start 4 banks apart => reads tile 32 banks
#define SH_ROW_SHORTS 72          // 64 data + 8 pad shorts (row stride 144 B)

typedef __attribute__((ext_vector_type(8))) short    short8;
typedef __attribute__((ext_vector_type(4))) float    float4v;
typedef __attribute__((ext_vector_type(4))) unsigned uint4v;

__device__ __forceinline__ unsigned f2bf1(float f) {
  union { float f; unsigned u; } v; v.f = f;
  return (v.u + 0x7FFFu + ((v.u >> 16) & 1u)) >> 16;   // RNE fp32->bf16
}

// ---- fused kernel, ROUND-12: 2 samples per block ----
// Ledger (r5/r6 ablations): kernel dispatch ~23us = 3.0 prologue + 11.3
// main loop (8.3us MFMA-issue floor) + ~8us RAMP (dispatch-rate for 512
// block launches; Occupancy 31% vs 50% cap). This round attacks the ramp:
// 256 blocks x 1024 threads, waves 0-7 -> sample 2*bid, waves 8-15 ->
// 2*bid+1. Halves are byte-identical r8 pipelines with per-half
// xf/xcp/c0h/wred; shb/s2cl shared (prep once per block, 8 thr/shapelet).
// LDS 128,384 B -> 1 block/CU = same 16 waves/CU; VGPR capped 128 by
// __launch_bounds__(1024,4).
// Math per sample: d2 = c0[p] + s2c[s] - 2*cross(x, centered_s);
// C-init = -c0/2; g = max_p(cross - c0/2); out = sqrt(s2c - 2g).
// Masked windows (p>=1985) carry c0h = -INF. fmax tree in max3-fusable
// nested-triple form (associative -> exact).
__global__ __launch_bounds__(1024, 4)
void shapelet_fused(const float* __restrict__ x, const float* __restrict__ shg,
                    float* __restrict__ out) {
  __shared__ __align__(16) float xf[2][XF_N];
  __shared__ __align__(16) unsigned long long xcp[2][8][XCP_W];
  __shared__ float c0h[2][2048];
  __shared__ __align__(16) short shb[SS * SH_ROW_SHORTS];
  __shared__ float s2cl[SS];
  __shared__ float wred[2][8 * SS];

  const int t = threadIdx.x;
  const int half = t >> 9, th = t & 511;        // sample-half and thread-in-half
  const int b = blockIdx.x * 2 + half;
  const int lane = t & 63, wave = th >> 6;      // wave-in-half 0..7
  const int n = lane & 15, q = lane >> 4;
  const int pq = wave;                          // 8 window-groups of 256

  // ---- stage x[b] (8 KB per half) into LDS, zero-pad to XF_N ----
  for (int idx = th; idx < XF_N / 4; idx += 512) {
    const int g0 = 4 * idx;
    float4v v = {0.f, 0.f, 0.f, 0.f};
    if (g0 + 3 < TT) v = *(const float4v*)(x + (size_t)b * TT + g0);
    *(float4v*)(&xf[half][4 * idx]) = v;
  }

  // ---- shapelet prep ONCE per block: 1024 threads, 8 per shapelet ----
  // thread t: row s = t>>3, eighth part8 = t&7 (8 floats)
  {
    const int s = t >> 3, part8 = t & 7;
    const float4v* sp = (const float4v*)(shg + s * LL + part8 * 8);
    float4v r0 = sp[0], r1 = sp[1];
    float sum = ((r0[0] + r0[1]) + (r0[2] + r0[3])) +
                ((r1[0] + r1[1]) + (r1[2] + r1[3]));
    float sq = 0.f;
    sq = fmaf(r0[0], r0[0], sq); sq = fmaf(r0[1], r0[1], sq);
    sq = fmaf(r0[2], r0[2], sq); sq = fmaf(r0[3], r0[3], sq);
    sq = fmaf(r1[0], r1[0], sq); sq = fmaf(r1[1], r1[1], sq);
    sq = fmaf(r1[2], r1[2], sq); sq = fmaf(r1[3], r1[3], sq);
    sum += __shfl_xor(sum, 1); sum += __shfl_xor(sum, 2); sum += __shfl_xor(sum, 4);
    sq  += __shfl_xor(sq, 1);  sq  += __shfl_xor(sq, 2);  sq  += __shfl_xor(sq, 4);
    const float mean = sum * (1.f / 64.f);

    unsigned pk0 = f2bf1(r0[0] - mean) | (f2bf1(r0[1] - mean) << 16);
    unsigned pk1 = f2bf1(r0[2] - mean) | (f2bf1(r0[3] - mean) << 16);
    unsigned pk2 = f2bf1(r1[0] - mean) | (f2bf1(r1[1] - mean) << 16);
    unsigned pk3 = f2bf1(r1[2] - mean) | (f2bf1(r1[3] - mean) << 16);
    unsigned* shbw = (unsigned*)shb;
    uint4v wv = {pk0, pk1, pk2, pk3};
    *(uint4v*)(shbw + s * (SH_ROW_SHORTS / 2) + part8 * 4) = wv;  // 16B aligned
    if (part8 == 0) s2cl[s] = sq;     // s2c = raw sum of squares
  }

  __syncthreads();

  // ---- B fragments from LDS shapelets: ALL 128 rows per wave ----
  short8 bf[2][8];
  #pragma unroll
  for (int st = 0; st < 8; ++st) {
    const int row = st * 16 + n;
    bf[0][st] = *(const short8*)(shb + row * SH_ROW_SHORTS + q * 8);
    bf[1][st] = *(const short8*)(shb + row * SH_ROW_SHORTS + 32 + q * 8);
  }

  // ---- build 8 element-shifted bf16 copies of xf (per half) ----
  for (int w = th; w < XCP_W; w += 512) {
    const float4v* xf4 = (const float4v*)&xf[half][0];
    float4v A = xf4[w], Bv = xf4[w + 1], Cv = xf4[w + 2];
    unsigned bfx[11];
    #pragma unroll
    for (int k = 0; k < 4; ++k) bfx[k] = f2bf1(A[k]);
    #pragma unroll
    for (int k = 0; k < 4; ++k) bfx[4 + k] = f2bf1(Bv[k]);
    #pragma unroll
    for (int k = 0; k < 3; ++k) bfx[8 + k] = f2bf1(Cv[k]);
    #pragma unroll
    for (int c = 0; c < 8; ++c) {
      unsigned long long pkw =
          (unsigned long long)bfx[c] |
          ((unsigned long long)bfx[c + 1] << 16) |
          ((unsigned long long)bfx[c + 2] << 32) |
          ((unsigned long long)bfx[c + 3] << 48);
      xcp[half][c][w] = pkw;
    }
  }

  // ---- window stats: thread th -> windows 4th..4th+3 (per half) ----
  {
    const float4v* xf4 = (const float4v*)&xf[half][0];
    float S = 0.f, Q = 0.f;
    float4v v0 = xf4[th];
    float4v vcur = v0;
    #pragma unroll 4
    for (int ch = 0; ch < 16; ++ch) {
      S += (vcur[0] + vcur[1]) + (vcur[2] + vcur[3]);
      Q = fmaf(vcur[0], vcur[0], Q); Q = fmaf(vcur[1], vcur[1], Q);
      Q = fmaf(vcur[2], vcur[2], Q); Q = fmaf(vcur[3], vcur[3], Q);
      vcur = xf4[th + ch + 1];          // after loop: vcur = xf4[th+16]
    }
    const float4v vN = vcur;
    const int p0s = 4 * th;
    #pragma unroll
    for (int r = 0; r < 4; ++r) {
      const bool valid = (p0s + r) < PP;
      const float c0 = Q - S * S * (1.f / 64.f);
      c0h[half][p0s + r] = valid ? (-0.5f * c0) : -INFINITY;
      if (r < 3) {
        const float vin = vN[r], vout = v0[r];
        S += vin - vout;
        Q += fmaf(vin, vin, -vout * vout);
      }
    }
  }

  __syncthreads();

  // ---- main MFMA loop: 16 iters x (1 A-read + 1 c0-read + 16 MFMA) ----
  // words: frag(mt,kb0) = w0+4mt ; frag(mt,kb1) = w0+4mt+8 = frag(mt+2,kb0).
  const int cc = n & 7;
  const int lw = 2 * q + 2 * (n >> 3);          // even => aligned ds_read_b128
  const unsigned long long* xc = &xcp[half][cc][0];
  const int base = pq * 256;
  const int w0 = (base >> 2) + lw;              // max 448+8+68 = 524 < 530

  float rmax[8];
  #pragma unroll
  for (int st = 0; st < 8; ++st) rmax[st] = -INFINITY;

  short8 h0 = *(const short8*)&xc[w0];          // frag(base,    kb0)
  short8 h1 = *(const short8*)&xc[w0 + 4];      // frag(base+16, kb0)

  #pragma unroll 2
  for (int mt = 0; mt < 16; ++mt) {
    const short8 l = *(const short8*)&xc[w0 + 4 * mt + 8];   // frag(p0, kb1)
    const float4v c0v = *(const float4v*)&c0h[half][base + 16 * mt + 4 * q];

    #pragma unroll
    for (int st = 0; st < 8; ++st) {
      float4v acc = __builtin_amdgcn_mfma_f32_16x16x32_bf16(h0, bf[0][st], c0v, 0, 0, 0);
      acc = __builtin_amdgcn_mfma_f32_16x16x32_bf16(l, bf[1][st], acc, 0, 0, 0);
      // nested pairs -> clang fuses v_max3_f32; max is associative (exact)
      const float t1 = fmaxf(fmaxf(acc[0], acc[1]), acc[2]);
      rmax[st] = fmaxf(fmaxf(t1, acc[3]), rmax[st]);
    }
    h0 = h1;          // frag(p0, kb1) == frag(p0+32, kb0)
    h1 = l;
  }

  // ---- reduce: across q (shfl), then across 8 waves (LDS), write out ----
  #pragma unroll
  for (int st = 0; st < 8; ++st) {
    float v = rmax[st];
    v = fmaxf(v, __shfl_xor(v, 16));
    v = fmaxf(v, __shfl_xor(v, 32));
    if (q == 0) wred[half][wave * SS + st * 16 + n] = v;
  }
  __syncthreads();

  if (th < SS) {
    float v = wred[half][th];
    #pragma unroll
    for (int w = 1; w < 8; ++w) v = fmaxf(v, wred[half][w * SS + th]);
    const float d2 = fmaf(-2.f, v, s2cl[th]);
    out[(size_t)b * SS + th] = sqrtf(fmaxf(d2, 0.f));
  }
}

extern "C" void kernel_launch(void* const* d_in, const int* in_sizes, int n_in,
                              void* d_out, int out_size, void* d_ws, size_t ws_size,
                              hipStream_t stream) {
  const float* x  = (const float*)d_in[0];
  const float* sh = (const float*)d_in[1];
  float* out = (float*)d_out;
  shapelet_fused<<<dim3(BB / 2), dim3(1024), 0, stream>>>(x, sh, out);
}